// Round 1
// baseline (380.779 us; speedup 1.0000x reference)
//
#include <hip/hip_runtime.h>

#define IMG_H 256
#define IMG_W 256
#define IMG_C 3
#define KS 33
#define PAD 16
#define THRESH 1e-4f
#define FH_PER 3   // 33 fh values split into 11 chunks of 3

// One thread per pixel, block = one image row (x = tid, coalesced over Kernels' x).
// grid = (256 rows, 11 fh-chunks). Each chunk accumulates 3*33 = 99 taps, then
// atomicAdd's its 3 channel partials into d_out (zeroed by memset before launch).
__global__ __launch_bounds__(256, 4)
void reblur_kernel(const float* __restrict__ img,
                   const float* __restrict__ ker,
                   float* __restrict__ out)
{
    const int x = threadIdx.x;          // 0..255
    const int y = blockIdx.x;           // 0..255
    const int chunk = blockIdx.y;       // 0..10
    const int fh0 = chunk * FH_PER;

    const int pix = y * IMG_W + x;
    const int plane = IMG_H * IMG_W;

    // Kernels layout: [k][y][x], k = fh*33 + fw
    const float* kp = ker + (size_t)(fh0 * KS) * plane + pix;

    float a0 = 0.f, a1 = 0.f, a2 = 0.f;
    const int xm = x - PAD;

    #pragma unroll
    for (int dfh = 0; dfh < FH_PER; ++dfh) {
        int yy = y + (fh0 + dfh) - PAD;
        yy = yy < 0 ? 0 : (yy > IMG_H - 1 ? IMG_H - 1 : yy);
        const float* __restrict__ r0 = img + yy * IMG_W;            // ch 0 row
        const float* __restrict__ r1 = r0 + plane;                  // ch 1 row
        const float* __restrict__ r2 = r1 + plane;                  // ch 2 row
        #pragma unroll
        for (int fw = 0; fw < KS; ++fw) {
            float w = *kp;
            kp += plane;                 // next tap k -> +65536 floats
            int xx = xm + fw;            // replication clamp
            xx = xx < 0 ? 0 : (xx > IMG_W - 1 ? IMG_W - 1 : xx);
            float we = (w > THRESH) ? w : 0.f;
            a0 = fmaf(we, r0[xx], a0);
            a1 = fmaf(we, r1[xx], a1);
            a2 = fmaf(we, r2[xx], a2);
        }
    }

    atomicAdd(out + pix,             a0);
    atomicAdd(out + plane + pix,     a1);
    atomicAdd(out + 2 * plane + pix, a2);
}

extern "C" void kernel_launch(void* const* d_in, const int* in_sizes, int n_in,
                              void* d_out, int out_size, void* d_ws, size_t ws_size,
                              hipStream_t stream) {
    const float* img = (const float*)d_in[0];   // [1,3,256,256] fp32
    const float* ker = (const float*)d_in[1];   // [1,1089,256,256] fp32
    float* out = (float*)d_out;                 // [1,3,256,256] fp32

    // d_out is poisoned 0xAA before every timed launch — zero it ourselves.
    hipMemsetAsync(out, 0, (size_t)out_size * sizeof(float), stream);

    dim3 grid(IMG_H, (KS + FH_PER - 1) / FH_PER);   // (256, 11)
    reblur_kernel<<<grid, IMG_W, 0, stream>>>(img, ker, out);
}